// Round 13
// baseline (365.053 us; speedup 1.0000x reference)
//
#include <hip/hip_runtime.h>

#define QLEN 1024
#define PASTN 3072
#define KVLEN 4096
#define HIDN 4096
#define NHEAD 32
#define NKVH 8
#define HDIM 128
#define NQKVC 6144  // 4096 (Wq) + 1024 (Wk) + 1024 (Wv)
#define PLANE ((size_t)QLEN * NQKVC)  // split-K partial plane stride (f32)

typedef unsigned short u16;
typedef __bf16 bf16x8 __attribute__((ext_vector_type(8)));
typedef float f32x4 __attribute__((ext_vector_type(4)));
typedef float f32x16 __attribute__((ext_vector_type(16)));
typedef u16 us8 __attribute__((ext_vector_type(8)));
typedef u16 us4 __attribute__((ext_vector_type(4)));

__device__ __forceinline__ u16 f2bf(float x) {
  unsigned u = __builtin_bit_cast(unsigned, x);
  u += 0x7fffu + ((u >> 16) & 1u);
  return (u16)(u >> 16);
}
__device__ __forceinline__ float bf2f(u16 b) {
  return __builtin_bit_cast(float, (unsigned)b << 16);
}

// async global->LDS, 16B per lane; LDS dest is wave-uniform base (+lane*16)
#define GLL16(gp, lp) __builtin_amdgcn_global_load_lds( \
    (const __attribute__((address_space(1))) void*)(gp), \
    (__attribute__((address_space(3))) void*)(lp), 16, 0, 0)

// ---------------------------------------------------------------- convert (hidden only)
__global__ __launch_bounds__(256) void cvt_kernel(const float* __restrict__ src,
                                                  u16* __restrict__ dst, int n) {
  int i = (blockIdx.x * 256 + threadIdx.x) * 4;
  if (i >= n) return;
  float4 f = *(const float4*)(src + i);
  ushort4 o = make_ushort4(f2bf(f.x), f2bf(f.y), f2bf(f.z), f2bf(f.w));
  *(ushort4*)(dst + i) = o;
}

// ---------------------------------------------------------------- GEMM (split-K, f32 B direct)
// C = A(bf16) * B(f32)^T, B staged f32 via global_load_lds (async), converted
// to bf16 at fragment-read time. BM=64, BN=128, BK=32, 4 waves, dbuf
// (A 2x4KB bf16, B 2x16KB f32 = 40KB). blockIdx.z = K-split.
// B swizzle: 8 slots/row (16B each), phys slot = logical ^ (row&7); row
// stride 128B ≡ 0 mod 32 banks -> fragment reads 2-way (free).
// A swizzle unchanged: slot = logical ^ ((row>>1)&3).
__global__ __launch_bounds__(256) void gemm_f32b_split(const u16* __restrict__ A,
                                                       const float* __restrict__ b0,
                                                       const float* __restrict__ b1,
                                                       const float* __restrict__ b2,
                                                       float* __restrict__ P,
                                                       int M, int N, int K, int Ks,
                                                       int S1, int S2) {
  __shared__ u16 Alds[2][64 * 32];
  __shared__ float Blds[2][128 * 32];
  const int tid = threadIdx.x, wid = tid >> 6, lane = tid & 63;
  const int m0 = blockIdx.y * 64, n0 = blockIdx.x * 128;
  const int z = blockIdx.z, zoff = z * Ks;
  const u16* Az = A + zoff;
  const float* bsrc;
  int rbase;
  if (n0 < S1)      { bsrc = b0; rbase = n0; }
  else if (n0 < S2) { bsrc = b1; rbase = n0 - S1; }
  else              { bsrc = b2; rbase = n0 - S2; }
  bsrc += zoff;
  float* Cz = P + (size_t)z * M * N;
  const int wm = (wid >> 1) * 32, wn = (wid & 1) * 64;
  const int l15 = lane & 15, l4 = lane >> 4;
  const int srowA = lane >> 2, spA = lane & 3;
  const int brow = lane >> 3, bch = lane & 7;  // B staging lane coords
  f32x4 acc[2][4] = {};
  auto stage = [&](int buf, int kt) {
    {  // A: 4KB total, 1KB per wave
      const int r = wid * 16 + srowA;
      GLL16(Az + (size_t)(m0 + r) * K + kt + (spA ^ ((r >> 1) & 3)) * 8,
            &Alds[buf][wid * 512]);
    }
#pragma unroll
    for (int i = 0; i < 4; ++i) {  // B: 16KB total, 4KB per wave
      const int w = wid * 4 + i;
      const int r = w * 8 + brow;
      const int c = bch ^ (r & 7);
      GLL16(bsrc + (size_t)(rbase + r) * K + kt + c * 4, &Blds[buf][w * 256]);
    }
  };
  stage(0, 0);
  __syncthreads();
  int cur = 0;
  for (int kt = 0; kt < Ks; kt += 32) {
    if (kt + 32 < Ks) stage(cur ^ 1, kt + 32);
    bf16x8 a[2], b[4];
#pragma unroll
    for (int i = 0; i < 2; ++i) {
      const int R = wm + i * 16 + l15;
      a[i] = *(const bf16x8*)&Alds[cur][R * 32 + (l4 ^ ((R >> 1) & 3)) * 8];
    }
#pragma unroll
    for (int j = 0; j < 4; ++j) {
      const int R = wn + j * 16 + l15;
      const int s0 = (2 * l4) ^ (R & 7), s1 = (2 * l4 + 1) ^ (R & 7);
      f32x4 lo = *(const f32x4*)&Blds[cur][R * 32 + s0 * 4];
      f32x4 hi = *(const f32x4*)&Blds[cur][R * 32 + s1 * 4];
#pragma unroll
      for (int jj = 0; jj < 4; ++jj) {
        b[j][jj] = (__bf16)lo[jj];
        b[j][4 + jj] = (__bf16)hi[jj];
      }
    }
#pragma unroll
    for (int i = 0; i < 2; ++i)
#pragma unroll
      for (int j = 0; j < 4; ++j)
        acc[i][j] = __builtin_amdgcn_mfma_f32_16x16x32_bf16(a[i], b[j], acc[i][j], 0, 0, 0);
    __syncthreads();
    cur ^= 1;
  }
#pragma unroll
  for (int i = 0; i < 2; ++i)
#pragma unroll
    for (int j = 0; j < 4; ++j) {
      int row = m0 + wm + i * 16 + l4 * 4;
      int col = n0 + wn + j * 16 + l15;
#pragma unroll
      for (int r = 0; r < 4; ++r) Cz[(size_t)(row + r) * N + col] = acc[i][j][r];
    }
}

// ---------------------------------------------------------------- split-K combine (f32 out)
__global__ __launch_bounds__(256) void comb2_f32(const float* __restrict__ P,
                                                 float* __restrict__ C, size_t MN) {
  const size_t i = ((size_t)blockIdx.x * 256 + threadIdx.x) * 4;
  f32x4 a = *(const f32x4*)(P + i);
  f32x4 b = *(const f32x4*)(P + MN + i);
  f32x4 o;
#pragma unroll
  for (int j = 0; j < 4; ++j) o[j] = a[j] + b[j];
  *(f32x4*)(C + i) = o;
}

// ---------------------------------------------------------------- RoPE on Q (from planes)
__global__ __launch_bounds__(256) void rope_q_kernel(const float* __restrict__ g,
                                                     u16* __restrict__ qr) {
  const float SC = 0.12753102f;  // log2(e)/sqrt(128)
  int idx = blockIdx.x * 256 + threadIdx.x;  // 1024*32*64
  int i = idx & 63, h = (idx >> 6) & 31, r = idx >> 11;
  float freq = __expf(-(float)i * (9.210340371976184f / 64.f));
  float angle = (float)(PASTN + r) * freq;
  float sn, cs;
  sincosf(angle, &sn, &cs);
  const size_t base = (size_t)r * NQKVC + h * HDIM + i;
  float x1 = g[base] + g[base + PLANE];
  float x2 = g[base + 64] + g[base + 64 + PLANE];
  int ob = r * HIDN + h * HDIM + i;
  qr[ob] = f2bf((x1 * cs - x2 * sn) * SC);
  qr[ob + 64] = f2bf((x2 * cs + x1 * sn) * SC);
}

// ---------------------------------------------------------------- K cache build (from planes)
__global__ __launch_bounds__(256) void repack_k_kernel(const float* __restrict__ past_k,
                                                       const float* __restrict__ g,
                                                       u16* __restrict__ kb) {
  int idx = blockIdx.x * 256 + threadIdx.x;  // 8*4096*128
  int d = idx & 127, kv = (idx >> 7) & 4095, hk = idx >> 19;
  float val;
  if (kv < PASTN) {
    val = past_k[((size_t)hk * PASTN + kv) * HDIM + d];
  } else {
    int r = kv - PASTN;
    const size_t b0 = (size_t)r * NQKVC + 4096 + hk * HDIM;
    float x = g[b0 + d] + g[b0 + d + PLANE];
    float xp = g[b0 + (d ^ 64)] + g[b0 + (d ^ 64) + PLANE];
    int i = d & 63;
    float freq = __expf(-(float)i * (9.210340371976184f / 64.f));
    float angle = (float)(PASTN + r) * freq;
    float sn, cs;
    sincosf(angle, &sn, &cs);
    val = (d < 64) ? (x * cs - xp * sn) : (x * cs + xp * sn);
  }
  kb[idx] = f2bf(val);
}

// ---------------------------------------------------------------- V^T cache build (from planes)
__global__ __launch_bounds__(256) void repack_vt_kernel(const float* __restrict__ past_v,
                                                        const float* __restrict__ g,
                                                        u16* __restrict__ vtb) {
  __shared__ u16 tile[32][136];
  int hk = blockIdx.y, kv0 = blockIdx.x * 32, tid = threadIdx.x;
  int j = tid >> 3, d0 = (tid & 7) * 16;
  if (kv0 < PASTN) {
    const float* src = past_v + ((size_t)hk * PASTN + kv0 + j) * HDIM + d0;
#pragma unroll
    for (int x = 0; x < 16; x += 4) {
      float4 f = *(const float4*)(src + x);
      tile[j][d0 + x] = f2bf(f.x);
      tile[j][d0 + x + 1] = f2bf(f.y);
      tile[j][d0 + x + 2] = f2bf(f.z);
      tile[j][d0 + x + 3] = f2bf(f.w);
    }
  } else {
    int r = kv0 - PASTN + j;
    const float* s0 = g + (size_t)r * NQKVC + 5120 + hk * HDIM + d0;
#pragma unroll
    for (int x = 0; x < 16; x += 4) {
      f32x4 a = *(const f32x4*)(s0 + x);
      f32x4 b = *(const f32x4*)(s0 + PLANE + x);
#pragma unroll
      for (int jj = 0; jj < 4; ++jj) tile[j][d0 + x + jj] = f2bf(a[jj] + b[jj]);
    }
  }
  __syncthreads();
  int d = tid >> 1, jb = (tid & 1) * 16;
  us8 o0, o1;
#pragma unroll
  for (int x = 0; x < 8; ++x) {
    o0[x] = tile[jb + x][d];
    o1[x] = tile[jb + 8 + x][d];
  }
  u16* dst = vtb + ((size_t)hk * HDIM + d) * KVLEN + kv0 + jb;
  *(us8*)dst = o0;
  *(us8*)(dst + 8) = o1;
}

// ---------------------------------------------------------------- flash attention
// (R9/R11 config, measured 108.7us): 32x32x16 MFMA, swapped operands
// (S^T = mfma(K,Q), q = lane&31), K rows permuted by pi (swap bits 2<->3) so
// S^T regs are the PV B-fragment; 8-wave blocks, q-tile 256, z-split-2,
// dbuf 64KB with prefetch-before-compute. Q arrives pre-scaled.
__global__ __launch_bounds__(512) void attn_kernel(const u16* __restrict__ q,
                                                   const u16* __restrict__ kc,
                                                   const u16* __restrict__ vt,
                                                   float* __restrict__ opart,
                                                   float* __restrict__ mlbuf) {
  __shared__ u16 Klds[2][64 * 128];
  __shared__ u16 Vlds[2][128 * 64];
  const int tid = threadIdx.x, wid = tid >> 6, lane = tid & 63;
  const int l31 = lane & 31, hi = lane >> 5, l15 = lane & 15;
  const int h = blockIdx.y, hk = h >> 2;
  const int q0 = blockIdx.x * 256;
  const int z = blockIdx.z;
  const int pid = h * 4 + blockIdx.x;
  const int qrow = q0 + wid * 32 + l31;
  bf16x8 qf[8];
  {
    const u16* qp = q + (size_t)qrow * HIDN + h * HDIM + hi * 8;
#pragma unroll
    for (int dk = 0; dk < 8; ++dk) qf[dk] = *(const bf16x8*)(qp + dk * 16);
  }
  float m_run = -1e30f, l_run = 0.f;
  f32x16 oacc[4] = {};
  const u16* kbase = kc + (size_t)hk * KVLEN * HDIM;
  const u16* vbase = vt + (size_t)hk * HDIM * KVLEN;
  const int ntiles = (PASTN + q0 + 256) >> 6;
  const int half = ntiles >> 1;
  const int t0 = z ? half : 0, t1 = z ? ntiles : half;
  const int qpos = PASTN + qrow;
  auto stage = [&](int buf, int kv0) {
#pragma unroll
    for (int i = 0; i < 2; ++i) {
      const int w = wid * 2 + i;
      const int p = w * 4 + (lane >> 4);
      const int key = (p & 0x33) | ((p & 4) << 1) | ((p & 8) >> 1);
      const int sl = (lane & 15) ^ (p & 15);
      GLL16(kbase + (size_t)(kv0 + key) * HDIM + sl * 8, &Klds[buf][w * 512]);
    }
#pragma unroll
    for (int i = 0; i < 2; ++i) {
      const int w = wid * 2 + i;
      const int d = w * 8 + (lane >> 3);
      const int sl = (lane & 7) ^ ((lane >> 3) & 7);
      GLL16(vbase + (size_t)d * KVLEN + kv0 + sl * 8, &Vlds[buf][w * 512]);
    }
  };
  stage(0, t0 << 6);
  __syncthreads();
  int cur = 0;
  for (int t = t0; t < t1; ++t) {
    if (t + 1 < t1) stage(cur ^ 1, (t + 1) << 6);
    const int kv0 = t << 6;
    const u16* Kb = Klds[cur];
    const u16* Vb = Vlds[cur];
    f32x16 s[2] = {};
    __builtin_amdgcn_s_setprio(1);
#pragma unroll
    for (int tt = 0; tt < 2; ++tt)
#pragma unroll
      for (int dk = 0; dk < 8; ++dk) {
        const int idx = (tt * 32 + l31) * 128 + (((dk * 2 + hi) ^ l15) * 8);
        bf16x8 kf = *(const bf16x8*)&Kb[idx];
        s[tt] = __builtin_amdgcn_mfma_f32_32x32x16_bf16(kf, qf[dk], s[tt], 0, 0, 0);
      }
    __builtin_amdgcn_s_setprio(0);
    float pm = -1e30f;
    if (kv0 + 63 > PASTN + q0) {
#pragma unroll
      for (int tt = 0; tt < 2; ++tt)
#pragma unroll
        for (int reg = 0; reg < 16; ++reg) {
          const int key = kv0 + tt * 32 + (reg & 7) + 8 * hi + ((reg & 8) << 1);
          float v = s[tt][reg];
          if (key > qpos) v = -1e30f;
          s[tt][reg] = v;
          pm = fmaxf(pm, v);
        }
    } else {
#pragma unroll
      for (int tt = 0; tt < 2; ++tt)
#pragma unroll
        for (int reg = 0; reg < 16; ++reg) pm = fmaxf(pm, s[tt][reg]);
    }
    pm = fmaxf(pm, __shfl_xor(pm, 32));
    if (!__all(pm <= m_run)) {  // skip-rescale
      const float mn = fmaxf(m_run, pm);
      const float corr = exp2f(m_run - mn);
      m_run = mn;
      l_run *= corr;
#pragma unroll
      for (int db = 0; db < 4; ++db)
#pragma unroll
        for (int r = 0; r < 16; ++r) oacc[db][r] *= corr;
    }
    float rs = 0.f;
#pragma unroll
    for (int tt = 0; tt < 2; ++tt)
#pragma unroll
      for (int reg = 0; reg < 16; ++reg) {
        const float p = exp2f(s[tt][reg] - m_run);
        s[tt][reg] = p;
        rs += p;
      }
    rs += __shfl_xor(rs, 32);
    l_run += rs;
    __builtin_amdgcn_s_setprio(1);
#pragma unroll
    for (int kc2 = 0; kc2 < 4; ++kc2) {
      bf16x8 pa;
#pragma unroll
      for (int j = 0; j < 8; ++j) pa[j] = (__bf16)s[kc2 >> 1][(kc2 & 1) * 8 + j];
#pragma unroll
      for (int db = 0; db < 4; ++db) {
        const int idx = (db * 32 + l31) * 64 + (((kc2 * 2 + hi) ^ (l31 & 7)) * 8);
        bf16x8 vf = *(const bf16x8*)&Vb[idx];
        oacc[db] = __builtin_amdgcn_mfma_f32_32x32x16_bf16(vf, pa, oacc[db], 0, 0, 0);
      }
    }
    __builtin_amdgcn_s_setprio(0);
    __syncthreads();
    cur ^= 1;
  }
  const int orow = wid * 32 + l31;
  float* op = opart + ((size_t)(z * 128 + pid) * 256 + orow) * 128;
#pragma unroll
  for (int db = 0; db < 4; ++db)
#pragma unroll
    for (int g = 0; g < 4; ++g) {
      f32x4 w4;
#pragma unroll
      for (int j = 0; j < 4; ++j) w4[j] = oacc[db][g * 4 + j];
      *(f32x4*)&op[db * 32 + g * 8 + hi * 4] = w4;
    }
  if (hi == 0) {
    float* mlp = mlbuf + ((size_t)(z * 128 + pid) * 256 + orow) * 2;
    mlp[0] = m_run;
    mlp[1] = l_run;
  }
}

// ---------------------------------------------------------------- combine partials (2-way)
__global__ __launch_bounds__(256) void attn_combine(const float* __restrict__ opart,
                                                    const float* __restrict__ mlbuf,
                                                    u16* __restrict__ o) {
  const int pid = blockIdx.x;  // h*4 + qt
  const int h = pid >> 2, qt = pid & 3;
  const int q2 = threadIdx.x >> 2, dc = (threadIdx.x & 3) * 32;
#pragma unroll
  for (int b = 0; b < 4; ++b) {
    const int q = b * 64 + q2;
    const float* ml0 = mlbuf + ((size_t)pid * 256 + q) * 2;
    const float* ml1 = mlbuf + ((size_t)(128 + pid) * 256 + q) * 2;
    const float m0 = ml0[0], l0 = ml0[1], m1 = ml1[0], l1 = ml1[1];
    const float m = fmaxf(m0, m1);
    const float w0 = exp2f(m0 - m), w1 = exp2f(m1 - m);
    const float inv = 1.f / (w0 * l0 + w1 * l1);
    const float* O0 = opart + ((size_t)pid * 256 + q) * 128 + dc;
    const float* O1 = opart + ((size_t)(128 + pid) * 256 + q) * 128 + dc;
    u16* dst = o + (size_t)(qt * 256 + q) * HIDN + h * HDIM + dc;
#pragma unroll
    for (int x = 0; x < 8; ++x) {
      f32x4 a = *(const f32x4*)(O0 + x * 4);
      f32x4 bb = *(const f32x4*)(O1 + x * 4);
      us4 w4;
#pragma unroll
      for (int j = 0; j < 4; ++j) w4[j] = f2bf((a[j] * w0 + bb[j] * w1) * inv);
      *(us4*)(dst + x * 4) = w4;
    }
  }
}

// ---------------------------------------------------------------- launch
extern "C" void kernel_launch(void* const* d_in, const int* in_sizes, int n_in,
                              void* d_out, int out_size, void* d_ws, size_t ws_size,
                              hipStream_t stream) {
  (void)in_sizes; (void)n_in; (void)out_size; (void)ws_size;
  const float* hidden = (const float*)d_in[0];
  const float* past_k = (const float*)d_in[3];
  const float* past_v = (const float*)d_in[4];
  const float* Wq = (const float*)d_in[5];
  const float* Wk = (const float*)d_in[6];
  const float* Wv = (const float*)d_in[7];
  const float* Wo = (const float*)d_in[8];
  float* out = (float*)d_out;

  // layout (~125MB): bf16 buffers + gpart (split-K planes; QKV planes live
  // until rope/repacks consume them, region reused by Wo GEMM) + attn partials.
  char* w = (char*)d_ws;
  u16* hiddenb = (u16*)w; w += (size_t)QLEN * HIDN * 2;          // 8MB
  u16* qrope   = (u16*)w; w += (size_t)QLEN * HIDN * 2;          // 8MB
  u16* kbuf    = (u16*)w; w += (size_t)NKVH * KVLEN * HDIM * 2;  // 8MB
  u16* vtbuf   = (u16*)w; w += (size_t)NKVH * HDIM * KVLEN * 2;  // 8MB
  u16* attnb   = (u16*)w; w += (size_t)QLEN * HIDN * 2;          // 8MB
  float* gpart = (float*)w; w += 2 * PLANE * sizeof(float);      // 50.3MB
  float* opart = (float*)w; w += (size_t)2 * 128 * 256 * 128 * 4;  // 33.5MB
  float* mlbuf = (float*)w;                                      // 0.5MB
  const size_t MN2 = (size_t)QLEN * HIDN;

  cvt_kernel<<<(QLEN * HIDN) / 1024, 256, 0, stream>>>(hidden, hiddenb, QLEN * HIDN);

  // QKV projection: B read f32 directly from Wq/Wk/Wv (no weight convert)
  gemm_f32b_split<<<dim3(NQKVC / 128, QLEN / 64, 2), 256, 0, stream>>>(
      hiddenb, Wq, Wk, Wv, gpart, QLEN, NQKVC, HIDN, HIDN / 2, 4096, 5120);

  rope_q_kernel<<<(QLEN * NHEAD * 64) / 256, 256, 0, stream>>>(gpart, qrope);
  repack_k_kernel<<<(NKVH * KVLEN * HDIM) / 256, 256, 0, stream>>>(past_k, gpart, kbuf);
  repack_vt_kernel<<<dim3(KVLEN / 32, NKVH), 256, 0, stream>>>(past_v, gpart, vtbuf);

  attn_kernel<<<dim3(QLEN / 256, NHEAD, 2), 512, 0, stream>>>(qrope, kbuf, vtbuf,
                                                              opart, mlbuf);
  attn_combine<<<128, 256, 0, stream>>>(opart, mlbuf, attnb);

  // output projection: B = Wo f32 direct
  gemm_f32b_split<<<dim3(HIDN / 128, QLEN / 64, 2), 256, 0, stream>>>(
      attnb, Wo, Wo, Wo, gpart, QLEN, HIDN, HIDN, HIDN / 2, HIDN, 2 * HIDN);
  comb2_f32<<<(int)(MN2 / 1024), 256, 0, stream>>>(gpart, out, MN2);
}

// Round 14
// 323.733 us; speedup vs baseline: 1.1276x; 1.1276x over previous
//
#include <hip/hip_runtime.h>

#define QLEN 1024
#define PASTN 3072
#define KVLEN 4096
#define HIDN 4096
#define NHEAD 32
#define NKVH 8
#define HDIM 128
#define NQKVC 6144  // 4096 (Wq) + 1024 (Wk) + 1024 (Wv)
#define PLANE ((size_t)QLEN * NQKVC)  // split-K partial plane stride (f32)

typedef unsigned short u16;
typedef __bf16 bf16x8 __attribute__((ext_vector_type(8)));
typedef float f32x4 __attribute__((ext_vector_type(4)));
typedef float f32x16 __attribute__((ext_vector_type(16)));
typedef u16 us8 __attribute__((ext_vector_type(8)));
typedef u16 us4 __attribute__((ext_vector_type(4)));

__device__ __forceinline__ u16 f2bf(float x) {
  unsigned u = __builtin_bit_cast(unsigned, x);
  u += 0x7fffu + ((u >> 16) & 1u);
  return (u16)(u >> 16);
}
__device__ __forceinline__ float bf2f(u16 b) {
  return __builtin_bit_cast(float, (unsigned)b << 16);
}

// async global->LDS, 16B per lane; LDS dest is wave-uniform base (+lane*16)
#define GLL16(gp, lp) __builtin_amdgcn_global_load_lds( \
    (const __attribute__((address_space(1))) void*)(gp), \
    (__attribute__((address_space(3))) void*)(lp), 16, 0, 0)

// ---------------------------------------------------------------- converts
// one launch for hidden + Wq + Wk + Wv + Wo (all f32 -> bf16).
__global__ __launch_bounds__(256) void cvt5_kernel(const float* __restrict__ hid,
                                                   const float* __restrict__ wq,
                                                   const float* __restrict__ wk,
                                                   const float* __restrict__ wv,
                                                   const float* __restrict__ woin,
                                                   u16* __restrict__ hb,
                                                   u16* __restrict__ wb,
                                                   u16* __restrict__ wob) {
  const int blk = blockIdx.x;
  const float* src;
  u16* dst;
  int off;
  if (blk < 4096)       { src = hid;  dst = hb;                       off = blk; }
  else if (blk < 20480) { src = wq;   dst = wb;                       off = blk - 4096; }
  else if (blk < 24576) { src = wk;   dst = wb + (size_t)4096 * HIDN; off = blk - 20480; }
  else if (blk < 28672) { src = wv;   dst = wb + (size_t)5120 * HIDN; off = blk - 24576; }
  else                  { src = woin; dst = wob;                      off = blk - 28672; }
  const int i = off * 1024 + threadIdx.x * 4;
  float4 f = *(const float4*)(src + i);
  ushort4 o = make_ushort4(f2bf(f.x), f2bf(f.y), f2bf(f.z), f2bf(f.w));
  *(ushort4*)(dst + i) = o;
}

// ---------------------------------------------------------------- GEMM (split-K, bf16 B)
// BM=64, BN=128, BK=32, 4 waves (each 32x64), dbuf 24KB (R6/R9 config —
// measured best). blockIdx.z = K-split; writes f32 partial plane z.
// Slot swizzle: stored slot s holds col-chunk s ^ ((row>>1)&3).
__global__ __launch_bounds__(256) void gemm_bt_split(const u16* __restrict__ A,
                                                     const u16* __restrict__ B,
                                                     float* __restrict__ P,
                                                     int M, int N, int K, int Ks) {
  __shared__ u16 Alds[2][64 * 32];
  __shared__ u16 Blds[2][128 * 32];
  const int tid = threadIdx.x, wid = tid >> 6, lane = tid & 63;
  const int m0 = blockIdx.y * 64, n0 = blockIdx.x * 128;
  const int z = blockIdx.z;
  const u16* Az = A + (size_t)z * Ks;
  const u16* Bz = B + (size_t)z * Ks;
  float* Cz = P + (size_t)z * M * N;
  const int wm = (wid >> 1) * 32, wn = (wid & 1) * 64;
  const int l15 = lane & 15, l4 = lane >> 4;
  const int srow = lane >> 2, sp = lane & 3;
  f32x4 acc[2][4] = {};
  auto stage = [&](int buf, int kt) {
    {
      const int r = wid * 16 + srow;
      GLL16(Az + (size_t)(m0 + r) * K + kt + (sp ^ ((r >> 1) & 3)) * 8,
            &Alds[buf][wid * 512]);
    }
#pragma unroll
    for (int i = 0; i < 2; ++i) {
      const int c = wid * 2 + i;
      const int r = c * 16 + srow;
      GLL16(Bz + (size_t)(n0 + r) * K + kt + (sp ^ ((r >> 1) & 3)) * 8,
            &Blds[buf][c * 512]);
    }
  };
  stage(0, 0);
  __syncthreads();
  int cur = 0;
  for (int kt = 0; kt < Ks; kt += 32) {
    if (kt + 32 < Ks) stage(cur ^ 1, kt + 32);
    bf16x8 a[2], b[4];
#pragma unroll
    for (int i = 0; i < 2; ++i) {
      const int R = wm + i * 16 + l15;
      a[i] = *(const bf16x8*)&Alds[cur][R * 32 + (l4 ^ ((R >> 1) & 3)) * 8];
    }
#pragma unroll
    for (int j = 0; j < 4; ++j) {
      const int R = wn + j * 16 + l15;
      b[j] = *(const bf16x8*)&Blds[cur][R * 32 + (l4 ^ ((R >> 1) & 3)) * 8];
    }
#pragma unroll
    for (int i = 0; i < 2; ++i)
#pragma unroll
      for (int j = 0; j < 4; ++j)
        acc[i][j] = __builtin_amdgcn_mfma_f32_16x16x32_bf16(a[i], b[j], acc[i][j], 0, 0, 0);
    __syncthreads();
    cur ^= 1;
  }
#pragma unroll
  for (int i = 0; i < 2; ++i)
#pragma unroll
    for (int j = 0; j < 4; ++j) {
      int row = m0 + wm + i * 16 + l4 * 4;
      int col = n0 + wn + j * 16 + l15;
#pragma unroll
      for (int r = 0; r < 4; ++r) Cz[(size_t)(row + r) * N + col] = acc[i][j][r];
    }
}

// ---------------------------------------------------------------- split-K combine (f32 out)
__global__ __launch_bounds__(256) void comb2_f32(const float* __restrict__ P,
                                                 float* __restrict__ C, size_t MN) {
  const size_t i = ((size_t)blockIdx.x * 256 + threadIdx.x) * 4;
  f32x4 a = *(const f32x4*)(P + i);
  f32x4 b = *(const f32x4*)(P + MN + i);
  f32x4 o;
#pragma unroll
  for (int j = 0; j < 4; ++j) o[j] = a[j] + b[j];
  *(f32x4*)(C + i) = o;
}

// ---------------------------------------------------------------- RoPE on Q (from planes)
__global__ __launch_bounds__(256) void rope_q_kernel(const float* __restrict__ g,
                                                     u16* __restrict__ qr) {
  const float SC = 0.12753102f;  // log2(e)/sqrt(128)
  int idx = blockIdx.x * 256 + threadIdx.x;  // 1024*32*64
  int i = idx & 63, h = (idx >> 6) & 31, r = idx >> 11;
  float freq = __expf(-(float)i * (9.210340371976184f / 64.f));
  float angle = (float)(PASTN + r) * freq;
  float sn, cs;
  sincosf(angle, &sn, &cs);
  const size_t base = (size_t)r * NQKVC + h * HDIM + i;
  float x1 = g[base] + g[base + PLANE];
  float x2 = g[base + 64] + g[base + 64 + PLANE];
  int ob = r * HIDN + h * HDIM + i;
  qr[ob] = f2bf((x1 * cs - x2 * sn) * SC);
  qr[ob + 64] = f2bf((x2 * cs + x1 * sn) * SC);
}

// ---------------------------------------------------------------- K cache build (from planes)
__global__ __launch_bounds__(256) void repack_k_kernel(const float* __restrict__ past_k,
                                                       const float* __restrict__ g,
                                                       u16* __restrict__ kb) {
  int idx = blockIdx.x * 256 + threadIdx.x;  // 8*4096*128
  int d = idx & 127, kv = (idx >> 7) & 4095, hk = idx >> 19;
  float val;
  if (kv < PASTN) {
    val = past_k[((size_t)hk * PASTN + kv) * HDIM + d];
  } else {
    int r = kv - PASTN;
    const size_t b0 = (size_t)r * NQKVC + 4096 + hk * HDIM;
    float x = g[b0 + d] + g[b0 + d + PLANE];
    float xp = g[b0 + (d ^ 64)] + g[b0 + (d ^ 64) + PLANE];
    int i = d & 63;
    float freq = __expf(-(float)i * (9.210340371976184f / 64.f));
    float angle = (float)(PASTN + r) * freq;
    float sn, cs;
    sincosf(angle, &sn, &cs);
    val = (d < 64) ? (x * cs - xp * sn) : (x * cs + xp * sn);
  }
  kb[idx] = f2bf(val);
}

// ---------------------------------------------------------------- V^T cache build (from planes)
__global__ __launch_bounds__(256) void repack_vt_kernel(const float* __restrict__ past_v,
                                                        const float* __restrict__ g,
                                                        u16* __restrict__ vtb) {
  __shared__ u16 tile[32][136];
  int hk = blockIdx.y, kv0 = blockIdx.x * 32, tid = threadIdx.x;
  int j = tid >> 3, d0 = (tid & 7) * 16;
  if (kv0 < PASTN) {
    const float* src = past_v + ((size_t)hk * PASTN + kv0 + j) * HDIM + d0;
#pragma unroll
    for (int x = 0; x < 16; x += 4) {
      float4 f = *(const float4*)(src + x);
      tile[j][d0 + x] = f2bf(f.x);
      tile[j][d0 + x + 1] = f2bf(f.y);
      tile[j][d0 + x + 2] = f2bf(f.z);
      tile[j][d0 + x + 3] = f2bf(f.w);
    }
  } else {
    int r = kv0 - PASTN + j;
    const float* s0 = g + (size_t)r * NQKVC + 5120 + hk * HDIM + d0;
#pragma unroll
    for (int x = 0; x < 16; x += 4) {
      f32x4 a = *(const f32x4*)(s0 + x);
      f32x4 b = *(const f32x4*)(s0 + PLANE + x);
#pragma unroll
      for (int jj = 0; jj < 4; ++jj) tile[j][d0 + x + jj] = f2bf(a[jj] + b[jj]);
    }
  }
  __syncthreads();
  int d = tid >> 1, jb = (tid & 1) * 16;
  us8 o0, o1;
#pragma unroll
  for (int x = 0; x < 8; ++x) {
    o0[x] = tile[jb + x][d];
    o1[x] = tile[jb + 8 + x][d];
  }
  u16* dst = vtb + ((size_t)hk * HDIM + d) * KVLEN + kv0 + jb;
  *(us8*)dst = o0;
  *(us8*)(dst + 8) = o1;
}

// ---------------------------------------------------------------- flash attention
// (R9/R11 config, measured 108.7us): 32x32x16 MFMA, swapped operands
// (S^T = mfma(K,Q), q = lane&31), K rows permuted by pi (swap bits 2<->3) so
// S^T regs are the PV B-fragment; 8-wave blocks, q-tile 256, z-split-2,
// dbuf 64KB with prefetch-before-compute. Q arrives pre-scaled.
// Round 13: O-partials stored bf16 (halves partial traffic; error ~1e-3).
__global__ __launch_bounds__(512) void attn_kernel(const u16* __restrict__ q,
                                                   const u16* __restrict__ kc,
                                                   const u16* __restrict__ vt,
                                                   u16* __restrict__ opart,
                                                   float* __restrict__ mlbuf) {
  __shared__ u16 Klds[2][64 * 128];
  __shared__ u16 Vlds[2][128 * 64];
  const int tid = threadIdx.x, wid = tid >> 6, lane = tid & 63;
  const int l31 = lane & 31, hi = lane >> 5, l15 = lane & 15;
  const int h = blockIdx.y, hk = h >> 2;
  const int q0 = blockIdx.x * 256;
  const int z = blockIdx.z;
  const int pid = h * 4 + blockIdx.x;
  const int qrow = q0 + wid * 32 + l31;
  bf16x8 qf[8];
  {
    const u16* qp = q + (size_t)qrow * HIDN + h * HDIM + hi * 8;
#pragma unroll
    for (int dk = 0; dk < 8; ++dk) qf[dk] = *(const bf16x8*)(qp + dk * 16);
  }
  float m_run = -1e30f, l_run = 0.f;
  f32x16 oacc[4] = {};
  const u16* kbase = kc + (size_t)hk * KVLEN * HDIM;
  const u16* vbase = vt + (size_t)hk * HDIM * KVLEN;
  const int ntiles = (PASTN + q0 + 256) >> 6;
  const int half = ntiles >> 1;
  const int t0 = z ? half : 0, t1 = z ? ntiles : half;
  const int qpos = PASTN + qrow;
  auto stage = [&](int buf, int kv0) {
#pragma unroll
    for (int i = 0; i < 2; ++i) {
      const int w = wid * 2 + i;
      const int p = w * 4 + (lane >> 4);
      const int key = (p & 0x33) | ((p & 4) << 1) | ((p & 8) >> 1);
      const int sl = (lane & 15) ^ (p & 15);
      GLL16(kbase + (size_t)(kv0 + key) * HDIM + sl * 8, &Klds[buf][w * 512]);
    }
#pragma unroll
    for (int i = 0; i < 2; ++i) {
      const int w = wid * 2 + i;
      const int d = w * 8 + (lane >> 3);
      const int sl = (lane & 7) ^ ((lane >> 3) & 7);
      GLL16(vbase + (size_t)d * KVLEN + kv0 + sl * 8, &Vlds[buf][w * 512]);
    }
  };
  stage(0, t0 << 6);
  __syncthreads();
  int cur = 0;
  for (int t = t0; t < t1; ++t) {
    if (t + 1 < t1) stage(cur ^ 1, (t + 1) << 6);
    const int kv0 = t << 6;
    const u16* Kb = Klds[cur];
    const u16* Vb = Vlds[cur];
    f32x16 s[2] = {};
    __builtin_amdgcn_s_setprio(1);
#pragma unroll
    for (int tt = 0; tt < 2; ++tt)
#pragma unroll
      for (int dk = 0; dk < 8; ++dk) {
        const int idx = (tt * 32 + l31) * 128 + (((dk * 2 + hi) ^ l15) * 8);
        bf16x8 kf = *(const bf16x8*)&Kb[idx];
        s[tt] = __builtin_amdgcn_mfma_f32_32x32x16_bf16(kf, qf[dk], s[tt], 0, 0, 0);
      }
    __builtin_amdgcn_s_setprio(0);
    float pm = -1e30f;
    if (kv0 + 63 > PASTN + q0) {
#pragma unroll
      for (int tt = 0; tt < 2; ++tt)
#pragma unroll
        for (int reg = 0; reg < 16; ++reg) {
          const int key = kv0 + tt * 32 + (reg & 7) + 8 * hi + ((reg & 8) << 1);
          float v = s[tt][reg];
          if (key > qpos) v = -1e30f;
          s[tt][reg] = v;
          pm = fmaxf(pm, v);
        }
    } else {
#pragma unroll
      for (int tt = 0; tt < 2; ++tt)
#pragma unroll
        for (int reg = 0; reg < 16; ++reg) pm = fmaxf(pm, s[tt][reg]);
    }
    pm = fmaxf(pm, __shfl_xor(pm, 32));
    if (!__all(pm <= m_run)) {  // skip-rescale
      const float mn = fmaxf(m_run, pm);
      const float corr = exp2f(m_run - mn);
      m_run = mn;
      l_run *= corr;
#pragma unroll
      for (int db = 0; db < 4; ++db)
#pragma unroll
        for (int r = 0; r < 16; ++r) oacc[db][r] *= corr;
    }
    float rs = 0.f;
#pragma unroll
    for (int tt = 0; tt < 2; ++tt)
#pragma unroll
      for (int reg = 0; reg < 16; ++reg) {
        const float p = exp2f(s[tt][reg] - m_run);
        s[tt][reg] = p;
        rs += p;
      }
    rs += __shfl_xor(rs, 32);
    l_run += rs;
    __builtin_amdgcn_s_setprio(1);
#pragma unroll
    for (int kc2 = 0; kc2 < 4; ++kc2) {
      bf16x8 pa;
#pragma unroll
      for (int j = 0; j < 8; ++j) pa[j] = (__bf16)s[kc2 >> 1][(kc2 & 1) * 8 + j];
#pragma unroll
      for (int db = 0; db < 4; ++db) {
        const int idx = (db * 32 + l31) * 64 + (((kc2 * 2 + hi) ^ (l31 & 7)) * 8);
        bf16x8 vf = *(const bf16x8*)&Vb[idx];
        oacc[db] = __builtin_amdgcn_mfma_f32_32x32x16_bf16(vf, pa, oacc[db], 0, 0, 0);
      }
    }
    __builtin_amdgcn_s_setprio(0);
    __syncthreads();
    cur ^= 1;
  }
  // epilogue: bf16 unnormalized O^T partial + per-row (m,l)
  const int orow = wid * 32 + l31;
  u16* op = opart + ((size_t)(z * 128 + pid) * 256 + orow) * 128;
#pragma unroll
  for (int db = 0; db < 4; ++db)
#pragma unroll
    for (int g = 0; g < 4; ++g) {
      us4 w4;
#pragma unroll
      for (int j = 0; j < 4; ++j) w4[j] = f2bf(oacc[db][g * 4 + j]);
      *(us4*)&op[db * 32 + g * 8 + hi * 4] = w4;
    }
  if (hi == 0) {
    float* mlp = mlbuf + ((size_t)(z * 128 + pid) * 256 + orow) * 2;
    mlp[0] = m_run;
    mlp[1] = l_run;
  }
}

// ---------------------------------------------------------------- combine partials (2-way, bf16 in)
__global__ __launch_bounds__(256) void attn_combine(const u16* __restrict__ opart,
                                                    const float* __restrict__ mlbuf,
                                                    u16* __restrict__ o) {
  const int pid = blockIdx.x;  // h*4 + qt
  const int h = pid >> 2, qt = pid & 3;
  const int q2 = threadIdx.x >> 2, dc = (threadIdx.x & 3) * 32;
#pragma unroll
  for (int b = 0; b < 4; ++b) {
    const int q = b * 64 + q2;
    const float* ml0 = mlbuf + ((size_t)pid * 256 + q) * 2;
    const float* ml1 = mlbuf + ((size_t)(128 + pid) * 256 + q) * 2;
    const float m0 = ml0[0], l0 = ml0[1], m1 = ml1[0], l1 = ml1[1];
    const float m = fmaxf(m0, m1);
    const float w0 = exp2f(m0 - m), w1 = exp2f(m1 - m);
    const float inv = 1.f / (w0 * l0 + w1 * l1);
    const u16* O0 = opart + ((size_t)pid * 256 + q) * 128 + dc;
    const u16* O1 = opart + ((size_t)(128 + pid) * 256 + q) * 128 + dc;
    u16* dst = o + (size_t)(qt * 256 + q) * HIDN + h * HDIM + dc;
#pragma unroll
    for (int x = 0; x < 4; ++x) {
      us8 a8 = *(const us8*)(O0 + x * 8);
      us8 b8 = *(const us8*)(O1 + x * 8);
      us8 w8;
#pragma unroll
      for (int j = 0; j < 8; ++j)
        w8[j] = f2bf((bf2f(a8[j]) * w0 + bf2f(b8[j]) * w1) * inv);
      *(us8*)(dst + x * 8) = w8;
    }
  }
}

// ---------------------------------------------------------------- launch
extern "C" void kernel_launch(void* const* d_in, const int* in_sizes, int n_in,
                              void* d_out, int out_size, void* d_ws, size_t ws_size,
                              hipStream_t stream) {
  (void)in_sizes; (void)n_in; (void)out_size; (void)ws_size;
  const float* hidden = (const float*)d_in[0];
  const float* past_k = (const float*)d_in[3];
  const float* past_v = (const float*)d_in[4];
  const float* Wq = (const float*)d_in[5];
  const float* Wk = (const float*)d_in[6];
  const float* Wv = (const float*)d_in[7];
  const float* Wo = (const float*)d_in[8];
  float* out = (float*)d_out;

  // layout (~170MB): persistent bf16 buffers; gpart f32 region (QKV split-K
  // planes live until rope/repacks consume them, then reused by the Wo GEMM);
  // attn partials (bf16 O + f32 ml) alias the dead-after-GEMM1 wqkv region.
  char* w = (char*)d_ws;
  u16* hiddenb = (u16*)w; w += (size_t)QLEN * HIDN * 2;          // 8MB
  u16* wqkv    = (u16*)w; w += (size_t)NQKVC * HIDN * 2;         // 48MB (attn partials later)
  u16* wo      = (u16*)w; w += (size_t)HIDN * HIDN * 2;          // 32MB
  u16* qrope   = (u16*)w; w += (size_t)QLEN * HIDN * 2;          // 8MB
  u16* kbuf    = (u16*)w; w += (size_t)NKVH * KVLEN * HDIM * 2;  // 8MB
  u16* vtbuf   = (u16*)w; w += (size_t)NKVH * HDIM * KVLEN * 2;  // 8MB
  u16* attnb   = (u16*)w; w += (size_t)QLEN * HIDN * 2;          // 8MB
  float* gpart = (float*)w;                                      // 50.3MB
  u16* opart = wqkv;                                             // 16.8MB bf16
  float* mlbuf = (float*)(wqkv + (size_t)2 * 128 * 256 * 128);   // +0.5MB
  const size_t MN2 = (size_t)QLEN * HIDN;

  cvt5_kernel<<<45056, 256, 0, stream>>>(hidden, Wq, Wk, Wv, Wo, hiddenb, wqkv, wo);

  gemm_bt_split<<<dim3(NQKVC / 128, QLEN / 64, 2), 256, 0, stream>>>(
      hiddenb, wqkv, gpart, QLEN, NQKVC, HIDN, HIDN / 2);

  // consumers read the two f32 planes directly (no intermediate combine)
  rope_q_kernel<<<(QLEN * NHEAD * 64) / 256, 256, 0, stream>>>(gpart, qrope);
  repack_k_kernel<<<(NKVH * KVLEN * HDIM) / 256, 256, 0, stream>>>(past_k, gpart, kbuf);
  repack_vt_kernel<<<dim3(KVLEN / 32, NKVH), 256, 0, stream>>>(past_v, gpart, vtbuf);

  attn_kernel<<<dim3(QLEN / 256, NHEAD, 2), 512, 0, stream>>>(qrope, kbuf, vtbuf,
                                                              opart, mlbuf);
  attn_combine<<<128, 256, 0, stream>>>(opart, mlbuf, attnb);

  gemm_bt_split<<<dim3(HIDN / 128, QLEN / 64, 2), 256, 0, stream>>>(
      attnb, wo, gpart, QLEN, HIDN, HIDN, HIDN / 2);
  comb2_f32<<<(int)(MN2 / 1024), 256, 0, stream>>>(gpart, out, MN2);
}

// Round 15
// 305.684 us; speedup vs baseline: 1.1942x; 1.0590x over previous
//
#include <hip/hip_runtime.h>

#define QLEN 1024
#define PASTN 3072
#define KVLEN 4096
#define HIDN 4096
#define NHEAD 32
#define NKVH 8
#define HDIM 128
#define NQKVC 6144  // 4096 (Wq) + 1024 (Wk) + 1024 (Wv)
#define PLANE ((size_t)QLEN * NQKVC)  // split-K partial plane stride (f32)

typedef unsigned short u16;
typedef __bf16 bf16x8 __attribute__((ext_vector_type(8)));
typedef float f32x4 __attribute__((ext_vector_type(4)));
typedef float f32x16 __attribute__((ext_vector_type(16)));
typedef u16 us8 __attribute__((ext_vector_type(8)));
typedef u16 us4 __attribute__((ext_vector_type(4)));

__device__ __forceinline__ u16 f2bf(float x) {
  unsigned u = __builtin_bit_cast(unsigned, x);
  u += 0x7fffu + ((u >> 16) & 1u);
  return (u16)(u >> 16);
}
__device__ __forceinline__ float bf2f(u16 b) {
  return __builtin_bit_cast(float, (unsigned)b << 16);
}

// async global->LDS, 16B per lane; LDS dest is wave-uniform base (+lane*16)
#define GLL16(gp, lp) __builtin_amdgcn_global_load_lds( \
    (const __attribute__((address_space(1))) void*)(gp), \
    (__attribute__((address_space(3))) void*)(lp), 16, 0, 0)

// ---------------------------------------------------------------- converts
// one launch for hidden + Wq + Wk + Wv + Wo (all f32 -> bf16).
__global__ __launch_bounds__(256) void cvt5_kernel(const float* __restrict__ hid,
                                                   const float* __restrict__ wq,
                                                   const float* __restrict__ wk,
                                                   const float* __restrict__ wv,
                                                   const float* __restrict__ woin,
                                                   u16* __restrict__ hb,
                                                   u16* __restrict__ wb,
                                                   u16* __restrict__ wob) {
  const int blk = blockIdx.x;
  const float* src;
  u16* dst;
  int off;
  if (blk < 4096)       { src = hid;  dst = hb;                       off = blk; }
  else if (blk < 20480) { src = wq;   dst = wb;                       off = blk - 4096; }
  else if (blk < 24576) { src = wk;   dst = wb + (size_t)4096 * HIDN; off = blk - 20480; }
  else if (blk < 28672) { src = wv;   dst = wb + (size_t)5120 * HIDN; off = blk - 24576; }
  else                  { src = woin; dst = wob;                      off = blk - 28672; }
  const int i = off * 1024 + threadIdx.x * 4;
  float4 f = *(const float4*)(src + i);
  ushort4 o = make_ushort4(f2bf(f.x), f2bf(f.y), f2bf(f.z), f2bf(f.w));
  *(ushort4*)(dst + i) = o;
}

// ---------------------------------------------------------------- GEMM (split-K, 128x128)
// Round 14: 128x128 tile (R8-verified structure) + z2 split-K (R9-verified
// residency fix). BK=32, 4 waves (each 64x64), dbuf 32KB. 8 ds_read_b128 per
// 16 MFMA (0.5 read/MFMA vs 0.75 for the 64x128 tile).
// Slot swizzle: stored slot s holds col-chunk s ^ ((row>>1)&3).
__global__ __launch_bounds__(256) void gemm_bt_split(const u16* __restrict__ A,
                                                     const u16* __restrict__ B,
                                                     float* __restrict__ P,
                                                     int M, int N, int K, int Ks) {
  __shared__ u16 Alds[2][128 * 32];
  __shared__ u16 Blds[2][128 * 32];
  const int tid = threadIdx.x, wid = tid >> 6, lane = tid & 63;
  const int m0 = blockIdx.y * 128, n0 = blockIdx.x * 128;
  const int z = blockIdx.z;
  const u16* Az = A + (size_t)z * Ks;
  const u16* Bz = B + (size_t)z * Ks;
  float* Cz = P + (size_t)z * M * N;
  const int wm = (wid >> 1) * 64, wn = (wid & 1) * 64;
  const int l15 = lane & 15, l4 = lane >> 4;
  const int srow = lane >> 2;
  const int scol = ((lane & 3) ^ ((lane >> 3) & 3)) * 8;  // pre-swizzled source chunk
  f32x4 acc[4][4] = {};
  auto stage = [&](int buf, int kt) {
#pragma unroll
    for (int i = 0; i < 2; ++i) {
      const int c = wid * 2 + i;
      const int row = c * 16 + srow;
      GLL16(Az + (size_t)(m0 + row) * K + kt + scol, &Alds[buf][c * 512]);
      GLL16(Bz + (size_t)(n0 + row) * K + kt + scol, &Blds[buf][c * 512]);
    }
  };
  stage(0, 0);
  __syncthreads();
  int cur = 0;
  for (int kt = 0; kt < Ks; kt += 32) {
    if (kt + 32 < Ks) stage(cur ^ 1, kt + 32);
    bf16x8 a[4], b[4];
#pragma unroll
    for (int i = 0; i < 4; ++i) {
      const int R = wm + i * 16 + l15;
      a[i] = *(const bf16x8*)&Alds[cur][R * 32 + (l4 ^ ((R >> 1) & 3)) * 8];
    }
#pragma unroll
    for (int j = 0; j < 4; ++j) {
      const int R = wn + j * 16 + l15;
      b[j] = *(const bf16x8*)&Blds[cur][R * 32 + (l4 ^ ((R >> 1) & 3)) * 8];
    }
#pragma unroll
    for (int i = 0; i < 4; ++i)
#pragma unroll
      for (int j = 0; j < 4; ++j)
        acc[i][j] = __builtin_amdgcn_mfma_f32_16x16x32_bf16(a[i], b[j], acc[i][j], 0, 0, 0);
    __syncthreads();
    cur ^= 1;
  }
#pragma unroll
  for (int i = 0; i < 4; ++i)
#pragma unroll
    for (int j = 0; j < 4; ++j) {
      int row = m0 + wm + i * 16 + l4 * 4;
      int col = n0 + wn + j * 16 + l15;
#pragma unroll
      for (int r = 0; r < 4; ++r) Cz[(size_t)(row + r) * N + col] = acc[i][j][r];
    }
}

// ---------------------------------------------------------------- split-K combine (f32 out)
__global__ __launch_bounds__(256) void comb2_f32(const float* __restrict__ P,
                                                 float* __restrict__ C, size_t MN) {
  const size_t i = ((size_t)blockIdx.x * 256 + threadIdx.x) * 4;
  f32x4 a = *(const f32x4*)(P + i);
  f32x4 b = *(const f32x4*)(P + MN + i);
  f32x4 o;
#pragma unroll
  for (int j = 0; j < 4; ++j) o[j] = a[j] + b[j];
  *(f32x4*)(C + i) = o;
}

// ---------------------------------------------------------------- RoPE on Q (from planes)
__global__ __launch_bounds__(256) void rope_q_kernel(const float* __restrict__ g,
                                                     u16* __restrict__ qr) {
  const float SC = 0.12753102f;  // log2(e)/sqrt(128)
  int idx = blockIdx.x * 256 + threadIdx.x;  // 1024*32*64
  int i = idx & 63, h = (idx >> 6) & 31, r = idx >> 11;
  float freq = __expf(-(float)i * (9.210340371976184f / 64.f));
  float angle = (float)(PASTN + r) * freq;
  float sn, cs;
  sincosf(angle, &sn, &cs);
  const size_t base = (size_t)r * NQKVC + h * HDIM + i;
  float x1 = g[base] + g[base + PLANE];
  float x2 = g[base + 64] + g[base + 64 + PLANE];
  int ob = r * HIDN + h * HDIM + i;
  qr[ob] = f2bf((x1 * cs - x2 * sn) * SC);
  qr[ob + 64] = f2bf((x2 * cs + x1 * sn) * SC);
}

// ---------------------------------------------------------------- K cache build (from planes)
__global__ __launch_bounds__(256) void repack_k_kernel(const float* __restrict__ past_k,
                                                       const float* __restrict__ g,
                                                       u16* __restrict__ kb) {
  int idx = blockIdx.x * 256 + threadIdx.x;  // 8*4096*128
  int d = idx & 127, kv = (idx >> 7) & 4095, hk = idx >> 19;
  float val;
  if (kv < PASTN) {
    val = past_k[((size_t)hk * PASTN + kv) * HDIM + d];
  } else {
    int r = kv - PASTN;
    const size_t b0 = (size_t)r * NQKVC + 4096 + hk * HDIM;
    float x = g[b0 + d] + g[b0 + d + PLANE];
    float xp = g[b0 + (d ^ 64)] + g[b0 + (d ^ 64) + PLANE];
    int i = d & 63;
    float freq = __expf(-(float)i * (9.210340371976184f / 64.f));
    float angle = (float)(PASTN + r) * freq;
    float sn, cs;
    sincosf(angle, &sn, &cs);
    val = (d < 64) ? (x * cs - xp * sn) : (x * cs + xp * sn);
  }
  kb[idx] = f2bf(val);
}

// ---------------------------------------------------------------- V^T cache build (from planes)
__global__ __launch_bounds__(256) void repack_vt_kernel(const float* __restrict__ past_v,
                                                        const float* __restrict__ g,
                                                        u16* __restrict__ vtb) {
  __shared__ u16 tile[32][136];
  int hk = blockIdx.y, kv0 = blockIdx.x * 32, tid = threadIdx.x;
  int j = tid >> 3, d0 = (tid & 7) * 16;
  if (kv0 < PASTN) {
    const float* src = past_v + ((size_t)hk * PASTN + kv0 + j) * HDIM + d0;
#pragma unroll
    for (int x = 0; x < 16; x += 4) {
      float4 f = *(const float4*)(src + x);
      tile[j][d0 + x] = f2bf(f.x);
      tile[j][d0 + x + 1] = f2bf(f.y);
      tile[j][d0 + x + 2] = f2bf(f.z);
      tile[j][d0 + x + 3] = f2bf(f.w);
    }
  } else {
    int r = kv0 - PASTN + j;
    const float* s0 = g + (size_t)r * NQKVC + 5120 + hk * HDIM + d0;
#pragma unroll
    for (int x = 0; x < 16; x += 4) {
      f32x4 a = *(const f32x4*)(s0 + x);
      f32x4 b = *(const f32x4*)(s0 + PLANE + x);
#pragma unroll
      for (int jj = 0; jj < 4; ++jj) tile[j][d0 + x + jj] = f2bf(a[jj] + b[jj]);
    }
  }
  __syncthreads();
  int d = tid >> 1, jb = (tid & 1) * 16;
  us8 o0, o1;
#pragma unroll
  for (int x = 0; x < 8; ++x) {
    o0[x] = tile[jb + x][d];
    o1[x] = tile[jb + 8 + x][d];
  }
  u16* dst = vtb + ((size_t)hk * HDIM + d) * KVLEN + kv0 + jb;
  *(us8*)dst = o0;
  *(us8*)(dst + 8) = o1;
}

// ---------------------------------------------------------------- flash attention
// (R9/R11/R13 config, measured ~109us): 32x32x16 MFMA, swapped operands
// (S^T = mfma(K,Q), q = lane&31), K rows permuted by pi (swap bits 2<->3) so
// S^T regs are the PV B-fragment; 8-wave blocks, q-tile 256, z-split-2,
// dbuf 64KB with prefetch-before-compute. Q arrives pre-scaled; bf16 partials.
__global__ __launch_bounds__(512) void attn_kernel(const u16* __restrict__ q,
                                                   const u16* __restrict__ kc,
                                                   const u16* __restrict__ vt,
                                                   u16* __restrict__ opart,
                                                   float* __restrict__ mlbuf) {
  __shared__ u16 Klds[2][64 * 128];
  __shared__ u16 Vlds[2][128 * 64];
  const int tid = threadIdx.x, wid = tid >> 6, lane = tid & 63;
  const int l31 = lane & 31, hi = lane >> 5, l15 = lane & 15;
  const int h = blockIdx.y, hk = h >> 2;
  const int q0 = blockIdx.x * 256;
  const int z = blockIdx.z;
  const int pid = h * 4 + blockIdx.x;
  const int qrow = q0 + wid * 32 + l31;
  bf16x8 qf[8];
  {
    const u16* qp = q + (size_t)qrow * HIDN + h * HDIM + hi * 8;
#pragma unroll
    for (int dk = 0; dk < 8; ++dk) qf[dk] = *(const bf16x8*)(qp + dk * 16);
  }
  float m_run = -1e30f, l_run = 0.f;
  f32x16 oacc[4] = {};
  const u16* kbase = kc + (size_t)hk * KVLEN * HDIM;
  const u16* vbase = vt + (size_t)hk * HDIM * KVLEN;
  const int ntiles = (PASTN + q0 + 256) >> 6;
  const int half = ntiles >> 1;
  const int t0 = z ? half : 0, t1 = z ? ntiles : half;
  const int qpos = PASTN + qrow;
  auto stage = [&](int buf, int kv0) {
#pragma unroll
    for (int i = 0; i < 2; ++i) {
      const int w = wid * 2 + i;
      const int p = w * 4 + (lane >> 4);
      const int key = (p & 0x33) | ((p & 4) << 1) | ((p & 8) >> 1);
      const int sl = (lane & 15) ^ (p & 15);
      GLL16(kbase + (size_t)(kv0 + key) * HDIM + sl * 8, &Klds[buf][w * 512]);
    }
#pragma unroll
    for (int i = 0; i < 2; ++i) {
      const int w = wid * 2 + i;
      const int d = w * 8 + (lane >> 3);
      const int sl = (lane & 7) ^ ((lane >> 3) & 7);
      GLL16(vbase + (size_t)d * KVLEN + kv0 + sl * 8, &Vlds[buf][w * 512]);
    }
  };
  stage(0, t0 << 6);
  __syncthreads();
  int cur = 0;
  for (int t = t0; t < t1; ++t) {
    if (t + 1 < t1) stage(cur ^ 1, (t + 1) << 6);
    const int kv0 = t << 6;
    const u16* Kb = Klds[cur];
    const u16* Vb = Vlds[cur];
    f32x16 s[2] = {};
    __builtin_amdgcn_s_setprio(1);
#pragma unroll
    for (int tt = 0; tt < 2; ++tt)
#pragma unroll
      for (int dk = 0; dk < 8; ++dk) {
        const int idx = (tt * 32 + l31) * 128 + (((dk * 2 + hi) ^ l15) * 8);
        bf16x8 kf = *(const bf16x8*)&Kb[idx];
        s[tt] = __builtin_amdgcn_mfma_f32_32x32x16_bf16(kf, qf[dk], s[tt], 0, 0, 0);
      }
    __builtin_amdgcn_s_setprio(0);
    float pm = -1e30f;
    if (kv0 + 63 > PASTN + q0) {
#pragma unroll
      for (int tt = 0; tt < 2; ++tt)
#pragma unroll
        for (int reg = 0; reg < 16; ++reg) {
          const int key = kv0 + tt * 32 + (reg & 7) + 8 * hi + ((reg & 8) << 1);
          float v = s[tt][reg];
          if (key > qpos) v = -1e30f;
          s[tt][reg] = v;
          pm = fmaxf(pm, v);
        }
    } else {
#pragma unroll
      for (int tt = 0; tt < 2; ++tt)
#pragma unroll
        for (int reg = 0; reg < 16; ++reg) pm = fmaxf(pm, s[tt][reg]);
    }
    pm = fmaxf(pm, __shfl_xor(pm, 32));
    if (!__all(pm <= m_run)) {  // skip-rescale
      const float mn = fmaxf(m_run, pm);
      const float corr = exp2f(m_run - mn);
      m_run = mn;
      l_run *= corr;
#pragma unroll
      for (int db = 0; db < 4; ++db)
#pragma unroll
        for (int r = 0; r < 16; ++r) oacc[db][r] *= corr;
    }
    float rs = 0.f;
#pragma unroll
    for (int tt = 0; tt < 2; ++tt)
#pragma unroll
      for (int reg = 0; reg < 16; ++reg) {
        const float p = exp2f(s[tt][reg] - m_run);
        s[tt][reg] = p;
        rs += p;
      }
    rs += __shfl_xor(rs, 32);
    l_run += rs;
    __builtin_amdgcn_s_setprio(1);
#pragma unroll
    for (int kc2 = 0; kc2 < 4; ++kc2) {
      bf16x8 pa;
#pragma unroll
      for (int j = 0; j < 8; ++j) pa[j] = (__bf16)s[kc2 >> 1][(kc2 & 1) * 8 + j];
#pragma unroll
      for (int db = 0; db < 4; ++db) {
        const int idx = (db * 32 + l31) * 64 + (((kc2 * 2 + hi) ^ (l31 & 7)) * 8);
        bf16x8 vf = *(const bf16x8*)&Vb[idx];
        oacc[db] = __builtin_amdgcn_mfma_f32_32x32x16_bf16(vf, pa, oacc[db], 0, 0, 0);
      }
    }
    __builtin_amdgcn_s_setprio(0);
    __syncthreads();
    cur ^= 1;
  }
  // epilogue: bf16 unnormalized O^T partial + per-row (m,l)
  const int orow = wid * 32 + l31;
  u16* op = opart + ((size_t)(z * 128 + pid) * 256 + orow) * 128;
#pragma unroll
  for (int db = 0; db < 4; ++db)
#pragma unroll
    for (int g = 0; g < 4; ++g) {
      us4 w4;
#pragma unroll
      for (int j = 0; j < 4; ++j) w4[j] = f2bf(oacc[db][g * 4 + j]);
      *(us4*)&op[db * 32 + g * 8 + hi * 4] = w4;
    }
  if (hi == 0) {
    float* mlp = mlbuf + ((size_t)(z * 128 + pid) * 256 + orow) * 2;
    mlp[0] = m_run;
    mlp[1] = l_run;
  }
}

// ---------------------------------------------------------------- combine partials (2-way, bf16 in)
__global__ __launch_bounds__(256) void attn_combine(const u16* __restrict__ opart,
                                                    const float* __restrict__ mlbuf,
                                                    u16* __restrict__ o) {
  const int pid = blockIdx.x;  // h*4 + qt
  const int h = pid >> 2, qt = pid & 3;
  const int q2 = threadIdx.x >> 2, dc = (threadIdx.x & 3) * 32;
#pragma unroll
  for (int b = 0; b < 4; ++b) {
    const int q = b * 64 + q2;
    const float* ml0 = mlbuf + ((size_t)pid * 256 + q) * 2;
    const float* ml1 = mlbuf + ((size_t)(128 + pid) * 256 + q) * 2;
    const float m0 = ml0[0], l0 = ml0[1], m1 = ml1[0], l1 = ml1[1];
    const float m = fmaxf(m0, m1);
    const float w0 = exp2f(m0 - m), w1 = exp2f(m1 - m);
    const float inv = 1.f / (w0 * l0 + w1 * l1);
    const u16* O0 = opart + ((size_t)pid * 256 + q) * 128 + dc;
    const u16* O1 = opart + ((size_t)(128 + pid) * 256 + q) * 128 + dc;
    u16* dst = o + (size_t)(qt * 256 + q) * HIDN + h * HDIM + dc;
#pragma unroll
    for (int x = 0; x < 4; ++x) {
      us8 a8 = *(const us8*)(O0 + x * 8);
      us8 b8 = *(const us8*)(O1 + x * 8);
      us8 w8;
#pragma unroll
      for (int j = 0; j < 8; ++j)
        w8[j] = f2bf((bf2f(a8[j]) * w0 + bf2f(b8[j]) * w1) * inv);
      *(us8*)(dst + x * 8) = w8;
    }
  }
}

// ---------------------------------------------------------------- launch
extern "C" void kernel_launch(void* const* d_in, const int* in_sizes, int n_in,
                              void* d_out, int out_size, void* d_ws, size_t ws_size,
                              hipStream_t stream) {
  (void)in_sizes; (void)n_in; (void)out_size; (void)ws_size;
  const float* hidden = (const float*)d_in[0];
  const float* past_k = (const float*)d_in[3];
  const float* past_v = (const float*)d_in[4];
  const float* Wq = (const float*)d_in[5];
  const float* Wk = (const float*)d_in[6];
  const float* Wv = (const float*)d_in[7];
  const float* Wo = (const float*)d_in[8];
  float* out = (float*)d_out;

  // layout (~170MB): persistent bf16 buffers; gpart f32 region (QKV split-K
  // planes live until rope/repacks consume them, then reused by the Wo GEMM);
  // attn partials (bf16 O + f32 ml) alias the dead-after-GEMM1 wqkv region.
  char* w = (char*)d_ws;
  u16* hiddenb = (u16*)w; w += (size_t)QLEN * HIDN * 2;          // 8MB
  u16* wqkv    = (u16*)w; w += (size_t)NQKVC * HIDN * 2;         // 48MB (attn partials later)
  u16* wo      = (u16*)w; w += (size_t)HIDN * HIDN * 2;          // 32MB
  u16* qrope   = (u16*)w; w += (size_t)QLEN * HIDN * 2;          // 8MB
  u16* kbuf    = (u16*)w; w += (size_t)NKVH * KVLEN * HDIM * 2;  // 8MB
  u16* vtbuf   = (u16*)w; w += (size_t)NKVH * HDIM * KVLEN * 2;  // 8MB
  u16* attnb   = (u16*)w; w += (size_t)QLEN * HIDN * 2;          // 8MB
  float* gpart = (float*)w;                                      // 50.3MB
  u16* opart = wqkv;                                             // 16.8MB bf16
  float* mlbuf = (float*)(wqkv + (size_t)2 * 128 * 256 * 128);   // +0.5MB
  const size_t MN2 = (size_t)QLEN * HIDN;

  cvt5_kernel<<<45056, 256, 0, stream>>>(hidden, Wq, Wk, Wv, Wo, hiddenb, wqkv, wo);

  gemm_bt_split<<<dim3(NQKVC / 128, QLEN / 128, 2), 256, 0, stream>>>(
      hiddenb, wqkv, gpart, QLEN, NQKVC, HIDN, HIDN / 2);

  // consumers read the two f32 planes directly (no intermediate combine)
  rope_q_kernel<<<(QLEN * NHEAD * 64) / 256, 256, 0, stream>>>(gpart, qrope);
  repack_k_kernel<<<(NKVH * KVLEN * HDIM) / 256, 256, 0, stream>>>(past_k, gpart, kbuf);
  repack_vt_kernel<<<dim3(KVLEN / 32, NKVH), 256, 0, stream>>>(past_v, gpart, vtbuf);

  attn_kernel<<<dim3(QLEN / 256, NHEAD, 2), 512, 0, stream>>>(qrope, kbuf, vtbuf,
                                                              opart, mlbuf);
  attn_combine<<<128, 256, 0, stream>>>(opart, mlbuf, attnb);

  gemm_bt_split<<<dim3(HIDN / 128, QLEN / 128, 2), 256, 0, stream>>>(
      attnb, wo, gpart, QLEN, HIDN, HIDN, HIDN / 2);
  comb2_f32<<<(int)(MN2 / 1024), 256, 0, stream>>>(gpart, out, MN2);
}

// Round 16
// 305.639 us; speedup vs baseline: 1.1944x; 1.0001x over previous
//
#include <hip/hip_runtime.h>

#define QLEN 1024
#define PASTN 3072
#define KVLEN 4096
#define HIDN 4096
#define NHEAD 32
#define NKVH 8
#define HDIM 128
#define NQKVC 6144  // 4096 (Wq) + 1024 (Wk) + 1024 (Wv)
#define PLANE ((size_t)QLEN * NQKVC)  // split-K partial plane stride (f32)

typedef unsigned short u16;
typedef __bf16 bf16x8 __attribute__((ext_vector_type(8)));
typedef float f32x4 __attribute__((ext_vector_type(4)));
typedef float f32x16 __attribute__((ext_vector_type(16)));
typedef u16 us8 __attribute__((ext_vector_type(8)));
typedef u16 us4 __attribute__((ext_vector_type(4)));

__device__ __forceinline__ u16 f2bf(float x) {
  unsigned u = __builtin_bit_cast(unsigned, x);
  u += 0x7fffu + ((u >> 16) & 1u);
  return (u16)(u >> 16);
}
__device__ __forceinline__ float bf2f(u16 b) {
  return __builtin_bit_cast(float, (unsigned)b << 16);
}

// async global->LDS, 16B per lane; LDS dest is wave-uniform base (+lane*16)
#define GLL16(gp, lp) __builtin_amdgcn_global_load_lds( \
    (const __attribute__((address_space(1))) void*)(gp), \
    (__attribute__((address_space(3))) void*)(lp), 16, 0, 0)

// ---------------------------------------------------------------- converts
// one launch for hidden + Wq + Wk + Wv + Wo (all f32 -> bf16).
__global__ __launch_bounds__(256) void cvt5_kernel(const float* __restrict__ hid,
                                                   const float* __restrict__ wq,
                                                   const float* __restrict__ wk,
                                                   const float* __restrict__ wv,
                                                   const float* __restrict__ woin,
                                                   u16* __restrict__ hb,
                                                   u16* __restrict__ wb,
                                                   u16* __restrict__ wob) {
  const int blk = blockIdx.x;
  const float* src;
  u16* dst;
  int off;
  if (blk < 4096)       { src = hid;  dst = hb;                       off = blk; }
  else if (blk < 20480) { src = wq;   dst = wb;                       off = blk - 4096; }
  else if (blk < 24576) { src = wk;   dst = wb + (size_t)4096 * HIDN; off = blk - 20480; }
  else if (blk < 28672) { src = wv;   dst = wb + (size_t)5120 * HIDN; off = blk - 24576; }
  else                  { src = woin; dst = wob;                      off = blk - 28672; }
  const int i = off * 1024 + threadIdx.x * 4;
  float4 f = *(const float4*)(src + i);
  ushort4 o = make_ushort4(f2bf(f.x), f2bf(f.y), f2bf(f.z), f2bf(f.w));
  *(ushort4*)(dst + i) = o;
}

// ---------------------------------------------------------------- GEMM (split-K, 128x128)
// 128x128 tile + z2 split-K (R14-measured best). BK=32, 4 waves (each 64x64),
// dbuf 32KB. Slot swizzle: stored slot s holds col-chunk s ^ ((row>>1)&3).
__global__ __launch_bounds__(256) void gemm_bt_split(const u16* __restrict__ A,
                                                     const u16* __restrict__ B,
                                                     float* __restrict__ P,
                                                     int M, int N, int K, int Ks) {
  __shared__ u16 Alds[2][128 * 32];
  __shared__ u16 Blds[2][128 * 32];
  const int tid = threadIdx.x, wid = tid >> 6, lane = tid & 63;
  const int m0 = blockIdx.y * 128, n0 = blockIdx.x * 128;
  const int z = blockIdx.z;
  const u16* Az = A + (size_t)z * Ks;
  const u16* Bz = B + (size_t)z * Ks;
  float* Cz = P + (size_t)z * M * N;
  const int wm = (wid >> 1) * 64, wn = (wid & 1) * 64;
  const int l15 = lane & 15, l4 = lane >> 4;
  const int srow = lane >> 2;
  const int scol = ((lane & 3) ^ ((lane >> 3) & 3)) * 8;  // pre-swizzled source chunk
  f32x4 acc[4][4] = {};
  auto stage = [&](int buf, int kt) {
#pragma unroll
    for (int i = 0; i < 2; ++i) {
      const int c = wid * 2 + i;
      const int row = c * 16 + srow;
      GLL16(Az + (size_t)(m0 + row) * K + kt + scol, &Alds[buf][c * 512]);
      GLL16(Bz + (size_t)(n0 + row) * K + kt + scol, &Blds[buf][c * 512]);
    }
  };
  stage(0, 0);
  __syncthreads();
  int cur = 0;
  for (int kt = 0; kt < Ks; kt += 32) {
    if (kt + 32 < Ks) stage(cur ^ 1, kt + 32);
    bf16x8 a[4], b[4];
#pragma unroll
    for (int i = 0; i < 4; ++i) {
      const int R = wm + i * 16 + l15;
      a[i] = *(const bf16x8*)&Alds[cur][R * 32 + (l4 ^ ((R >> 1) & 3)) * 8];
    }
#pragma unroll
    for (int j = 0; j < 4; ++j) {
      const int R = wn + j * 16 + l15;
      b[j] = *(const bf16x8*)&Blds[cur][R * 32 + (l4 ^ ((R >> 1) & 3)) * 8];
    }
#pragma unroll
    for (int i = 0; i < 4; ++i)
#pragma unroll
      for (int j = 0; j < 4; ++j)
        acc[i][j] = __builtin_amdgcn_mfma_f32_16x16x32_bf16(a[i], b[j], acc[i][j], 0, 0, 0);
    __syncthreads();
    cur ^= 1;
  }
#pragma unroll
  for (int i = 0; i < 4; ++i)
#pragma unroll
    for (int j = 0; j < 4; ++j) {
      int row = m0 + wm + i * 16 + l4 * 4;
      int col = n0 + wn + j * 16 + l15;
#pragma unroll
      for (int r = 0; r < 4; ++r) Cz[(size_t)(row + r) * N + col] = acc[i][j][r];
    }
}

// ---------------------------------------------------------------- split-K combine (f32 out)
__global__ __launch_bounds__(256) void comb2_f32(const float* __restrict__ P,
                                                 float* __restrict__ C, size_t MN) {
  const size_t i = ((size_t)blockIdx.x * 256 + threadIdx.x) * 4;
  f32x4 a = *(const f32x4*)(P + i);
  f32x4 b = *(const f32x4*)(P + MN + i);
  f32x4 o;
#pragma unroll
  for (int j = 0; j < 4; ++j) o[j] = a[j] + b[j];
  *(f32x4*)(C + i) = o;
}

// ---------------------------------------------------------------- RoPE on Q (from planes)
__global__ __launch_bounds__(256) void rope_q_kernel(const float* __restrict__ g,
                                                     u16* __restrict__ qr) {
  const float SC = 0.12753102f;  // log2(e)/sqrt(128)
  int idx = blockIdx.x * 256 + threadIdx.x;  // 1024*32*64
  int i = idx & 63, h = (idx >> 6) & 31, r = idx >> 11;
  float freq = __expf(-(float)i * (9.210340371976184f / 64.f));
  float angle = (float)(PASTN + r) * freq;
  float sn, cs;
  sincosf(angle, &sn, &cs);
  const size_t base = (size_t)r * NQKVC + h * HDIM + i;
  float x1 = g[base] + g[base + PLANE];
  float x2 = g[base + 64] + g[base + 64 + PLANE];
  int ob = r * HIDN + h * HDIM + i;
  qr[ob] = f2bf((x1 * cs - x2 * sn) * SC);
  qr[ob + 64] = f2bf((x2 * cs + x1 * sn) * SC);
}

// ---------------------------------------------------------------- K cache build (from planes)
__global__ __launch_bounds__(256) void repack_k_kernel(const float* __restrict__ past_k,
                                                       const float* __restrict__ g,
                                                       u16* __restrict__ kb) {
  int idx = blockIdx.x * 256 + threadIdx.x;  // 8*4096*128
  int d = idx & 127, kv = (idx >> 7) & 4095, hk = idx >> 19;
  float val;
  if (kv < PASTN) {
    val = past_k[((size_t)hk * PASTN + kv) * HDIM + d];
  } else {
    int r = kv - PASTN;
    const size_t b0 = (size_t)r * NQKVC + 4096 + hk * HDIM;
    float x = g[b0 + d] + g[b0 + d + PLANE];
    float xp = g[b0 + (d ^ 64)] + g[b0 + (d ^ 64) + PLANE];
    int i = d & 63;
    float freq = __expf(-(float)i * (9.210340371976184f / 64.f));
    float angle = (float)(PASTN + r) * freq;
    float sn, cs;
    sincosf(angle, &sn, &cs);
    val = (d < 64) ? (x * cs - xp * sn) : (x * cs + xp * sn);
  }
  kb[idx] = f2bf(val);
}

// ---------------------------------------------------------------- V^T cache build (from planes)
__global__ __launch_bounds__(256) void repack_vt_kernel(const float* __restrict__ past_v,
                                                        const float* __restrict__ g,
                                                        u16* __restrict__ vtb) {
  __shared__ u16 tile[32][136];
  int hk = blockIdx.y, kv0 = blockIdx.x * 32, tid = threadIdx.x;
  int j = tid >> 3, d0 = (tid & 7) * 16;
  if (kv0 < PASTN) {
    const float* src = past_v + ((size_t)hk * PASTN + kv0 + j) * HDIM + d0;
#pragma unroll
    for (int x = 0; x < 16; x += 4) {
      float4 f = *(const float4*)(src + x);
      tile[j][d0 + x] = f2bf(f.x);
      tile[j][d0 + x + 1] = f2bf(f.y);
      tile[j][d0 + x + 2] = f2bf(f.z);
      tile[j][d0 + x + 3] = f2bf(f.w);
    }
  } else {
    int r = kv0 - PASTN + j;
    const float* s0 = g + (size_t)r * NQKVC + 5120 + hk * HDIM + d0;
#pragma unroll
    for (int x = 0; x < 16; x += 4) {
      f32x4 a = *(const f32x4*)(s0 + x);
      f32x4 b = *(const f32x4*)(s0 + PLANE + x);
#pragma unroll
      for (int jj = 0; jj < 4; ++jj) tile[j][d0 + x + jj] = f2bf(a[jj] + b[jj]);
    }
  }
  __syncthreads();
  int d = tid >> 1, jb = (tid & 1) * 16;
  us8 o0, o1;
#pragma unroll
  for (int x = 0; x < 8; ++x) {
    o0[x] = tile[jb + x][d];
    o1[x] = tile[jb + 8 + x][d];
  }
  u16* dst = vtb + ((size_t)hk * HDIM + d) * KVLEN + kv0 + jb;
  *(us8*)dst = o0;
  *(us8*)(dst + 8) = o1;
}

// ---------------------------------------------------------------- flash attention
// (R9/R11/R13 config + R15 XCD swizzle): 32x32x16 MFMA, swapped operands
// (S^T = mfma(K,Q), q = lane&31), K rows permuted by pi (swap bits 2<->3) so
// S^T regs are the PV B-fragment; 8-wave blocks, q-tile 256, z-split-2,
// dbuf 64KB with prefetch-before-compute. Q arrives pre-scaled; bf16 partials.
// R15: 1-D grid, hk = bid & 7 -> all 32 blocks sharing a kv-head land on one
// XCD (round-robin id->XCD); per-XCD K/V working set 2MB fits the 4MB L2.
__global__ __launch_bounds__(512) void attn_kernel(const u16* __restrict__ q,
                                                   const u16* __restrict__ kc,
                                                   const u16* __restrict__ vt,
                                                   u16* __restrict__ opart,
                                                   float* __restrict__ mlbuf) {
  __shared__ u16 Klds[2][64 * 128];
  __shared__ u16 Vlds[2][128 * 64];
  const int tid = threadIdx.x, wid = tid >> 6, lane = tid & 63;
  const int l31 = lane & 31, hi = lane >> 5, l15 = lane & 15;
  // XCD-aware decode: bid = hk + 8*(bx + 4*hsub + 16*z)
  const int bid = blockIdx.x;
  const int hk = bid & 7;
  const int rest = bid >> 3;
  const int bx = rest & 3;
  const int hsub = (rest >> 2) & 3;
  const int z = rest >> 4;
  const int h = hk * 4 + hsub;
  const int q0 = bx * 256;
  const int pid = h * 4 + bx;
  const int qrow = q0 + wid * 32 + l31;
  bf16x8 qf[8];
  {
    const u16* qp = q + (size_t)qrow * HIDN + h * HDIM + hi * 8;
#pragma unroll
    for (int dk = 0; dk < 8; ++dk) qf[dk] = *(const bf16x8*)(qp + dk * 16);
  }
  float m_run = -1e30f, l_run = 0.f;
  f32x16 oacc[4] = {};
  const u16* kbase = kc + (size_t)hk * KVLEN * HDIM;
  const u16* vbase = vt + (size_t)hk * HDIM * KVLEN;
  const int ntiles = (PASTN + q0 + 256) >> 6;
  const int half = ntiles >> 1;
  const int t0 = z ? half : 0, t1 = z ? ntiles : half;
  const int qpos = PASTN + qrow;
  auto stage = [&](int buf, int kv0) {
#pragma unroll
    for (int i = 0; i < 2; ++i) {
      const int w = wid * 2 + i;
      const int p = w * 4 + (lane >> 4);
      const int key = (p & 0x33) | ((p & 4) << 1) | ((p & 8) >> 1);
      const int sl = (lane & 15) ^ (p & 15);
      GLL16(kbase + (size_t)(kv0 + key) * HDIM + sl * 8, &Klds[buf][w * 512]);
    }
#pragma unroll
    for (int i = 0; i < 2; ++i) {
      const int w = wid * 2 + i;
      const int d = w * 8 + (lane >> 3);
      const int sl = (lane & 7) ^ ((lane >> 3) & 7);
      GLL16(vbase + (size_t)d * KVLEN + kv0 + sl * 8, &Vlds[buf][w * 512]);
    }
  };
  stage(0, t0 << 6);
  __syncthreads();
  int cur = 0;
  for (int t = t0; t < t1; ++t) {
    if (t + 1 < t1) stage(cur ^ 1, (t + 1) << 6);
    const int kv0 = t << 6;
    const u16* Kb = Klds[cur];
    const u16* Vb = Vlds[cur];
    f32x16 s[2] = {};
    __builtin_amdgcn_s_setprio(1);
#pragma unroll
    for (int tt = 0; tt < 2; ++tt)
#pragma unroll
      for (int dk = 0; dk < 8; ++dk) {
        const int idx = (tt * 32 + l31) * 128 + (((dk * 2 + hi) ^ l15) * 8);
        bf16x8 kf = *(const bf16x8*)&Kb[idx];
        s[tt] = __builtin_amdgcn_mfma_f32_32x32x16_bf16(kf, qf[dk], s[tt], 0, 0, 0);
      }
    __builtin_amdgcn_s_setprio(0);
    float pm = -1e30f;
    if (kv0 + 63 > PASTN + q0) {
#pragma unroll
      for (int tt = 0; tt < 2; ++tt)
#pragma unroll
        for (int reg = 0; reg < 16; ++reg) {
          const int key = kv0 + tt * 32 + (reg & 7) + 8 * hi + ((reg & 8) << 1);
          float v = s[tt][reg];
          if (key > qpos) v = -1e30f;
          s[tt][reg] = v;
          pm = fmaxf(pm, v);
        }
    } else {
#pragma unroll
      for (int tt = 0; tt < 2; ++tt)
#pragma unroll
        for (int reg = 0; reg < 16; ++reg) pm = fmaxf(pm, s[tt][reg]);
    }
    pm = fmaxf(pm, __shfl_xor(pm, 32));
    if (!__all(pm <= m_run)) {  // skip-rescale
      const float mn = fmaxf(m_run, pm);
      const float corr = exp2f(m_run - mn);
      m_run = mn;
      l_run *= corr;
#pragma unroll
      for (int db = 0; db < 4; ++db)
#pragma unroll
        for (int r = 0; r < 16; ++r) oacc[db][r] *= corr;
    }
    float rs = 0.f;
#pragma unroll
    for (int tt = 0; tt < 2; ++tt)
#pragma unroll
      for (int reg = 0; reg < 16; ++reg) {
        const float p = exp2f(s[tt][reg] - m_run);
        s[tt][reg] = p;
        rs += p;
      }
    rs += __shfl_xor(rs, 32);
    l_run += rs;
    __builtin_amdgcn_s_setprio(1);
#pragma unroll
    for (int kc2 = 0; kc2 < 4; ++kc2) {
      bf16x8 pa;
#pragma unroll
      for (int j = 0; j < 8; ++j) pa[j] = (__bf16)s[kc2 >> 1][(kc2 & 1) * 8 + j];
#pragma unroll
      for (int db = 0; db < 4; ++db) {
        const int idx = (db * 32 + l31) * 64 + (((kc2 * 2 + hi) ^ (l31 & 7)) * 8);
        bf16x8 vf = *(const bf16x8*)&Vb[idx];
        oacc[db] = __builtin_amdgcn_mfma_f32_32x32x16_bf16(vf, pa, oacc[db], 0, 0, 0);
      }
    }
    __builtin_amdgcn_s_setprio(0);
    __syncthreads();
    cur ^= 1;
  }
  // epilogue: bf16 unnormalized O^T partial + per-row (m,l)
  const int orow = wid * 32 + l31;
  u16* op = opart + ((size_t)(z * 128 + pid) * 256 + orow) * 128;
#pragma unroll
  for (int db = 0; db < 4; ++db)
#pragma unroll
    for (int g = 0; g < 4; ++g) {
      us4 w4;
#pragma unroll
      for (int j = 0; j < 4; ++j) w4[j] = f2bf(oacc[db][g * 4 + j]);
      *(us4*)&op[db * 32 + g * 8 + hi * 4] = w4;
    }
  if (hi == 0) {
    float* mlp = mlbuf + ((size_t)(z * 128 + pid) * 256 + orow) * 2;
    mlp[0] = m_run;
    mlp[1] = l_run;
  }
}

// ---------------------------------------------------------------- combine partials (2-way, bf16 in)
__global__ __launch_bounds__(256) void attn_combine(const u16* __restrict__ opart,
                                                    const float* __restrict__ mlbuf,
                                                    u16* __restrict__ o) {
  const int pid = blockIdx.x;  // h*4 + qt
  const int h = pid >> 2, qt = pid & 3;
  const int q2 = threadIdx.x >> 2, dc = (threadIdx.x & 3) * 32;
#pragma unroll
  for (int b = 0; b < 4; ++b) {
    const int q = b * 64 + q2;
    const float* ml0 = mlbuf + ((size_t)pid * 256 + q) * 2;
    const float* ml1 = mlbuf + ((size_t)(128 + pid) * 256 + q) * 2;
    const float m0 = ml0[0], l0 = ml0[1], m1 = ml1[0], l1 = ml1[1];
    const float m = fmaxf(m0, m1);
    const float w0 = exp2f(m0 - m), w1 = exp2f(m1 - m);
    const float inv = 1.f / (w0 * l0 + w1 * l1);
    const u16* O0 = opart + ((size_t)pid * 256 + q) * 128 + dc;
    const u16* O1 = opart + ((size_t)(128 + pid) * 256 + q) * 128 + dc;
    u16* dst = o + (size_t)(qt * 256 + q) * HIDN + h * HDIM + dc;
#pragma unroll
    for (int x = 0; x < 4; ++x) {
      us8 a8 = *(const us8*)(O0 + x * 8);
      us8 b8 = *(const us8*)(O1 + x * 8);
      us8 w8;
#pragma unroll
      for (int j = 0; j < 8; ++j)
        w8[j] = f2bf((bf2f(a8[j]) * w0 + bf2f(b8[j]) * w1) * inv);
      *(us8*)(dst + x * 8) = w8;
    }
  }
}

// ---------------------------------------------------------------- launch
extern "C" void kernel_launch(void* const* d_in, const int* in_sizes, int n_in,
                              void* d_out, int out_size, void* d_ws, size_t ws_size,
                              hipStream_t stream) {
  (void)in_sizes; (void)n_in; (void)out_size; (void)ws_size;
  const float* hidden = (const float*)d_in[0];
  const float* past_k = (const float*)d_in[3];
  const float* past_v = (const float*)d_in[4];
  const float* Wq = (const float*)d_in[5];
  const float* Wk = (const float*)d_in[6];
  const float* Wv = (const float*)d_in[7];
  const float* Wo = (const float*)d_in[8];
  float* out = (float*)d_out;

  // layout (~170MB): persistent bf16 buffers; gpart f32 region (QKV split-K
  // planes live until rope/repacks consume them, then reused by the Wo GEMM);
  // attn partials (bf16 O + f32 ml) alias the dead-after-GEMM1 wqkv region.
  char* w = (char*)d_ws;
  u16* hiddenb = (u16*)w; w += (size_t)QLEN * HIDN * 2;          // 8MB
  u16* wqkv    = (u16*)w; w += (size_t)NQKVC * HIDN * 2;         // 48MB (attn partials later)
  u16* wo      = (u16*)w; w += (size_t)HIDN * HIDN * 2;          // 32MB
  u16* qrope   = (u16*)w; w += (size_t)QLEN * HIDN * 2;          // 8MB
  u16* kbuf    = (u16*)w; w += (size_t)NKVH * KVLEN * HDIM * 2;  // 8MB
  u16* vtbuf   = (u16*)w; w += (size_t)NKVH * HDIM * KVLEN * 2;  // 8MB
  u16* attnb   = (u16*)w; w += (size_t)QLEN * HIDN * 2;          // 8MB
  float* gpart = (float*)w;                                      // 50.3MB
  u16* opart = wqkv;                                             // 16.8MB bf16
  float* mlbuf = (float*)(wqkv + (size_t)2 * 128 * 256 * 128);   // +0.5MB
  const size_t MN2 = (size_t)QLEN * HIDN;

  cvt5_kernel<<<45056, 256, 0, stream>>>(hidden, Wq, Wk, Wv, Wo, hiddenb, wqkv, wo);

  gemm_bt_split<<<dim3(NQKVC / 128, QLEN / 128, 2), 256, 0, stream>>>(
      hiddenb, wqkv, gpart, QLEN, NQKVC, HIDN, HIDN / 2);

  // consumers read the two f32 planes directly (no intermediate combine)
  rope_q_kernel<<<(QLEN * NHEAD * 64) / 256, 256, 0, stream>>>(gpart, qrope);
  repack_k_kernel<<<(NKVH * KVLEN * HDIM) / 256, 256, 0, stream>>>(past_k, gpart, kbuf);
  repack_vt_kernel<<<dim3(KVLEN / 32, NKVH), 256, 0, stream>>>(past_v, gpart, vtbuf);

  attn_kernel<<<256, 512, 0, stream>>>(qrope, kbuf, vtbuf, opart, mlbuf);
  attn_combine<<<128, 256, 0, stream>>>(opart, mlbuf, attnb);

  gemm_bt_split<<<dim3(HIDN / 128, QLEN / 128, 2), 256, 0, stream>>>(
      attnb, wo, gpart, QLEN, HIDN, HIDN, HIDN / 2);
  comb2_f32<<<(int)(MN2 / 1024), 256, 0, stream>>>(gpart, out, MN2);
}